// Round 5
// baseline (428.503 us; speedup 1.0000x reference)
//
#include <hip/hip_runtime.h>

#define D 128
#define RPB_BITS 9          // 512 rows per bucket; n<=131072 -> <=256 buckets
#define CH 8192             // edges per bucket_scatter block

typedef __attribute__((ext_vector_type(8))) short bf16x8;
typedef __attribute__((ext_vector_type(4))) float f32x4;

static __device__ __forceinline__ unsigned short f2bf(float f) {
    union { float f; unsigned u; } v; v.f = f;
    unsigned r = (v.u + 0x7fffu + ((v.u >> 16) & 1u)) >> 16;   // RNE
    return (unsigned short)r;
}
static __device__ __forceinline__ float bf2f(unsigned short s) {
    union { unsigned u; float f; } v; v.u = ((unsigned)s) << 16;
    return v.f;
}

// ---------------- W pre-conversion: fp32 [k][n] -> bf16 LDS image ----------------
// image[n*D + (k ^ ((n&7)<<3))] = bf16(W[k][n]); swizzle preserved within octets.
__global__ __launch_bounds__(256) void prep_w(
    const float* __restrict__ Wa, const float* __restrict__ Wb, const float* __restrict__ Wc,
    unsigned short* __restrict__ Ta, unsigned short* __restrict__ Tb, unsigned short* __restrict__ Tc)
{
    const int m = blockIdx.x >> 3;
    const float* W = (m == 0) ? Wa : ((m == 1) ? Wb : Wc);
    unsigned short* T = (m == 0) ? Ta : ((m == 1) ? Tb : Tc);
    const int t = ((blockIdx.x & 7) << 8) + threadIdx.x;   // 0..2047
    const int n = t >> 4;
    const int k0 = (t & 15) << 3;
    bf16x8 hv;
    #pragma unroll
    for (int j = 0; j < 8; ++j)
        hv[j] = (short)f2bf(W[(size_t)(k0 + j) * D + n]);
    *(bf16x8*)&T[n * D + (k0 ^ ((n & 7) << 3))] = hv;
}

// ---------------- GEMM building blocks (BM=32, BN=128, K=128) ----------------
// linear 32KB copy of the preswizzled W image into LDS
static __device__ __forceinline__ void stage_Wimg(
    const unsigned short* __restrict__ Wt, unsigned short* Wh, int tid)
{
    #pragma unroll
    for (int i = 0; i < 8; ++i) {
        const int e = (tid << 3) + (i << 11);   // tid*8 + i*2048 elems
        *(uint4*)&Wh[e] = *(const uint4*)&Wt[e];
    }
}

static __device__ __forceinline__ void stage_X(
    const float* __restrict__ X, unsigned short* Xh, unsigned short* Xl,
    int row0, int nrows, int w, int l)
{
    const int k0 = (l & 15) << 3;
    #pragma unroll
    for (int i = 0; i < 2; ++i) {
        const int r = ((w + (i << 2)) << 2) + (l >> 4);   // 0..31
        bf16x8 hv, lv;
        if (row0 + r < nrows) {
            const float* xp = X + (size_t)(row0 + r) * D + k0;
            #pragma unroll
            for (int j = 0; j < 8; ++j) {
                float x = xp[j];
                unsigned short h = f2bf(x);
                hv[j] = (short)h;
                lv[j] = (short)f2bf(x - bf2f(h));   // split-bf16 residual
            }
        } else {
            #pragma unroll
            for (int j = 0; j < 8; ++j) { hv[j] = 0; lv[j] = 0; }
        }
        const int sw = k0 ^ ((r & 7) << 3);
        *(bf16x8*)&Xh[r * D + sw] = hv;
        *(bf16x8*)&Xl[r * D + sw] = lv;
    }
}

static __device__ __forceinline__ void mfma_compute(
    const unsigned short* Xh, const unsigned short* Xl, const unsigned short* Wh,
    f32x4 acc[4], int w, int l)
{
    const int rtile = (w >> 1) << 4;
    const int c0 = (w & 1) << 6;
    const int ra = rtile + (l & 15);
    #pragma unroll
    for (int kb = 0; kb < 4; ++kb) {
        const int kk0 = (kb << 5) + ((l >> 4) << 3);
        const int swa = kk0 ^ ((ra & 7) << 3);
        const bf16x8 ah = *(const bf16x8*)&Xh[ra * D + swa];
        const bf16x8 al = *(const bf16x8*)&Xl[ra * D + swa];
        #pragma unroll
        for (int ct = 0; ct < 4; ++ct) {
            const int n = c0 + (ct << 4) + (l & 15);
            const bf16x8 bh = *(const bf16x8*)&Wh[n * D + (kk0 ^ ((n & 7) << 3))];
            acc[ct] = __builtin_amdgcn_mfma_f32_16x16x32_bf16(ah, bh, acc[ct], 0, 0, 0);
            acc[ct] = __builtin_amdgcn_mfma_f32_16x16x32_bf16(al, bh, acc[ct], 0, 0, 0);
        }
    }
}

static __device__ __forceinline__ void epilogue_store(
    const f32x4 acc[4], const float* __restrict__ bias,
    unsigned short* __restrict__ H, int row0, int nrows, int w, int l)
{
    const int rtile = (w >> 1) << 4;
    const int c0 = (w & 1) << 6;
    #pragma unroll
    for (int ct = 0; ct < 4; ++ct) {
        const int col = c0 + (ct << 4) + (l & 15);
        const float bv = bias[col];
        #pragma unroll
        for (int j = 0; j < 4; ++j) {
            const int r = row0 + rtile + ((l >> 4) << 2) + j;
            if (r < nrows)
                H[(size_t)r * D + col] = f2bf(fmaxf(acc[ct][j] + bv, 0.f));
        }
    }
}

// ---------------- K1: GEMM0 blocks + bucket-prehist blocks fused ----------------
__global__ __launch_bounds__(256) void gemm0_prehist(
    const float* __restrict__ X, const unsigned short* __restrict__ Wt,
    const float* __restrict__ bias, unsigned short* __restrict__ H, int nrows,
    int gemm_grid,
    const int* __restrict__ dstf, const int* __restrict__ dstr,
    int Ef, int Er, int* __restrict__ gbc)
{
    __shared__ unsigned short Xh[32 * D];
    __shared__ unsigned short Xl[32 * D];
    __shared__ unsigned short Wh[128 * D];
    __shared__ int lcnt[512];
    const int tid = threadIdx.x;
    if ((int)blockIdx.x < gemm_grid) {
        const int w = tid >> 6, l = tid & 63;
        const int row0 = blockIdx.x * 32;
        stage_Wimg(Wt, Wh, tid);
        stage_X(X, Xh, Xl, row0, nrows, w, l);
        __syncthreads();
        f32x4 acc[4] = {};
        mfma_compute(Xh, Xl, Wh, acc, w, l);
        epilogue_store(acc, bias, H, row0, nrows, w, l);
    } else {
        lcnt[tid] = 0; lcnt[tid + 256] = 0;
        __syncthreads();
        const int nb = gridDim.x - gemm_grid;
        const int bid = blockIdx.x - gemm_grid;
        const int tot = Ef + Er;
        for (int i = bid * 256 + tid; i < tot; i += nb * 256) {
            int idx = (i < Ef) ? (dstf[i] >> RPB_BITS)
                               : (256 + (dstr[i - Ef] >> RPB_BITS));
            atomicAdd(&lcnt[idx], 1);
        }
        __syncthreads();
        if (lcnt[tid])       atomicAdd(&gbc[tid],       lcnt[tid]);
        if (lcnt[tid + 256]) atomicAdd(&gbc[tid + 256], lcnt[tid + 256]);
    }
}

// ---------------- K2: per-rel exclusive scan of 256 bucket counts ----------------
__global__ void scan_buckets(const int* __restrict__ gbc, int* __restrict__ gbase,
                             int* __restrict__ gcur, int* rpf_n, int* rpr_n,
                             int Ef, int Er)
{
    __shared__ int ts[256];
    const int t = threadIdx.x;
    for (int r = 0; r < 2; ++r) {
        int v = gbc[r * 256 + t];
        ts[t] = v; __syncthreads();
        int incl = v;
        for (int o = 1; o < 256; o <<= 1) {
            int y = (t >= o) ? ts[t - o] : 0;
            __syncthreads();
            incl += y; ts[t] = incl;
            __syncthreads();
        }
        gbase[r * 256 + t] = incl - v;
        gcur[r * 256 + t]  = incl - v;
        __syncthreads();
    }
    if (t == 0) { *rpf_n = Ef; *rpr_n = Er; }
}

// ---------------- K3: scatter edges into bucket-major packed form ----------------
// pk word = src | (local_row << 18); src < 2^18, local_row < 512
__global__ __launch_bounds__(256) void bucket_scatter(
    const int* __restrict__ eif, const int* __restrict__ eir,
    int Ef, int Er, int chunks_f,
    int* __restrict__ gcur,
    unsigned* __restrict__ pk_f, unsigned* __restrict__ pk_r)
{
    __shared__ int cnt[256], off[256];
    const int t = threadIdx.x;
    const int cid = blockIdx.x;
    const int *src, *dst; unsigned* pk; int* cur; int base, E;
    if (cid < chunks_f) { base = cid * CH;              E = Ef; src = eif; dst = eif + Ef; pk = pk_f; cur = gcur; }
    else                { base = (cid - chunks_f) * CH; E = Er; src = eir; dst = eir + Er; pk = pk_r; cur = gcur + 256; }
    cnt[t] = 0;
    __syncthreads();
    for (int k = 0; k < CH / 256; ++k) {
        int e = base + t + k * 256;
        if (e < E) atomicAdd(&cnt[dst[e] >> RPB_BITS], 1);
    }
    __syncthreads();
    { int c = cnt[t]; if (c) off[t] = atomicAdd(&cur[t], c); }
    __syncthreads();
    for (int k = 0; k < CH / 256; ++k) {
        int e = base + t + k * 256;
        if (e < E) {
            int d = dst[e];
            int p = atomicAdd(&off[d >> RPB_BITS], 1);
            pk[p] = (unsigned)src[e] | ((unsigned)(d & 511) << 18);
        }
    }
}

// ---------------- K4: per-bucket CSR finalize (rowptr + esrc) ----------------
__global__ __launch_bounds__(256) void csr_finalize(
    const unsigned* __restrict__ pk_f, const unsigned* __restrict__ pk_r,
    const int* __restrict__ gbase, int Ef, int Er,
    int* __restrict__ rpf, int* __restrict__ rpr,
    int* __restrict__ esf, int* __restrict__ esr, int n)
{
    __shared__ int deg[512], cur[512], ts[256];
    const int t = threadIdx.x;
    const int rel = (int)blockIdx.x >> 8;
    const int b = (int)blockIdx.x & 255;
    const unsigned* pk = rel ? pk_r : pk_f;
    int* rp = rel ? rpr : rpf;
    int* es = rel ? esr : esf;
    const int E = rel ? Er : Ef;
    const int* gb = gbase + rel * 256;
    const int beg = gb[b];
    const int end = (b == 255) ? E : gb[b + 1];
    deg[t] = 0; deg[t + 256] = 0;
    __syncthreads();
    for (int j = beg + t; j < end; j += 256)
        atomicAdd(&deg[pk[j] >> 18], 1);
    __syncthreads();
    const int a0 = deg[2 * t], a1 = deg[2 * t + 1];
    const int s = a0 + a1;
    ts[t] = s; __syncthreads();
    int incl = s;
    for (int o = 1; o < 256; o <<= 1) {
        int y = (t >= o) ? ts[t - o] : 0;
        __syncthreads();
        incl += y; ts[t] = incl;
        __syncthreads();
    }
    const int ex = incl - s;
    const int row0 = b << RPB_BITS;
    if (row0 + 2 * t < n)     rp[row0 + 2 * t]     = beg + ex;
    if (row0 + 2 * t + 1 < n) rp[row0 + 2 * t + 1] = beg + ex + a0;
    cur[2 * t] = ex; cur[2 * t + 1] = ex + a0;
    __syncthreads();
    for (int j = beg + t; j < end; j += 256) {
        unsigned v = pk[j];
        int p = atomicAdd(&cur[v >> 18], 1);
        es[beg + p] = (int)(v & 0x3ffffu);
    }
}

// ---------------- fused: U1-tile segsum (regs) -> split-bf16 LDS -> dual GEMM ----
__global__ __launch_bounds__(256) void seg_dualgemm(
    const unsigned short* __restrict__ H0,
    const int* __restrict__ rp, const int* __restrict__ es,
    const unsigned short* __restrict__ Wt1, const float* __restrict__ b1,
    unsigned short* __restrict__ H1,
    const unsigned short* __restrict__ Wt2, const float* __restrict__ b2,
    unsigned short* __restrict__ H2,
    float* __restrict__ U1out, int nrows)
{
    __shared__ unsigned short Xh[32 * D];
    __shared__ unsigned short Xl[32 * D];
    __shared__ unsigned short Wh[2][128 * D];   // 64 KB
    const int tid = threadIdx.x;
    const int row0 = blockIdx.x * 32;

    stage_Wimg(Wt1, Wh[0], tid);
    if (Wt2) stage_Wimg(Wt2, Wh[1], tid);

    // segsum into registers: 8 lanes/row, 16 cols/lane
    const int rl = tid >> 3;              // local row 0..31
    const int r = row0 + rl;
    const int c0 = (tid & 7) << 4;        // col base
    float a[16];
    #pragma unroll
    for (int q = 0; q < 16; ++q) a[q] = 0.f;
    if (r < nrows) {
        const int beg = rp[r], end = rp[r + 1];
        for (int j = beg; j < end; ++j) {
            const unsigned short* hp = H0 + (size_t)es[j] * D + c0;
            const uint4 v0 = *(const uint4*)hp;
            const uint4 v1 = *(const uint4*)(hp + 8);
            const unsigned dw[8] = {v0.x, v0.y, v0.z, v0.w, v1.x, v1.y, v1.z, v1.w};
            #pragma unroll
            for (int q = 0; q < 8; ++q) {
                union { unsigned u; float f; } lo, hi;
                lo.u = dw[q] << 16; hi.u = dw[q] & 0xffff0000u;
                a[2 * q]     += lo.f;
                a[2 * q + 1] += hi.f;
            }
        }
        if (U1out) {
            float4* up = (float4*)(U1out + (size_t)r * D + c0);
            up[0] = make_float4(a[0], a[1], a[2], a[3]);
            up[1] = make_float4(a[4], a[5], a[6], a[7]);
            up[2] = make_float4(a[8], a[9], a[10], a[11]);
            up[3] = make_float4(a[12], a[13], a[14], a[15]);
        }
    }

    // split-bf16 into LDS (two octets: c0, c0+8)
    bf16x8 hv0, lv0, hv1, lv1;
    #pragma unroll
    for (int q = 0; q < 8; ++q) {
        unsigned short h0 = f2bf(a[q]);
        hv0[q] = (short)h0; lv0[q] = (short)f2bf(a[q] - bf2f(h0));
        unsigned short h1 = f2bf(a[q + 8]);
        hv1[q] = (short)h1; lv1[q] = (short)f2bf(a[q + 8] - bf2f(h1));
    }
    const int sw0 = c0 ^ ((rl & 7) << 3);
    const int sw1 = (c0 + 8) ^ ((rl & 7) << 3);
    *(bf16x8*)&Xh[rl * D + sw0] = hv0;
    *(bf16x8*)&Xl[rl * D + sw0] = lv0;
    *(bf16x8*)&Xh[rl * D + sw1] = hv1;
    *(bf16x8*)&Xl[rl * D + sw1] = lv1;
    __syncthreads();

    const int w = tid >> 6, l = tid & 63;
    {
        f32x4 acc[4] = {};
        mfma_compute(Xh, Xl, Wh[0], acc, w, l);
        epilogue_store(acc, b1, H1, row0, nrows, w, l);
    }
    if (Wt2) {
        f32x4 acc[4] = {};
        mfma_compute(Xh, Xl, Wh[1], acc, w, l);
        epilogue_store(acc, b2, H2, row0, nrows, w, l);
    }
}

// ---------------- segmented sum over bf16 H -> fp32 out (final, both rels) ------
static __device__ __forceinline__ void segsum_row(
    const unsigned short* __restrict__ H, const int* __restrict__ rp,
    const int* __restrict__ es, float* __restrict__ out, int row, int lane16)
{
    const int c = lane16 << 3;
    float a[8] = {0.f,0.f,0.f,0.f,0.f,0.f,0.f,0.f};
    const int beg = rp[row], end = rp[row + 1];
    int sNext = (beg < end) ? es[beg] : 0;
    for (int j = beg; j < end; ++j) {
        const int s = sNext;
        sNext = (j + 1 < end) ? es[j + 1] : 0;
        const uint4 v = *(const uint4*)(H + (size_t)s * D + c);
        const unsigned dw[4] = {v.x, v.y, v.z, v.w};
        #pragma unroll
        for (int q = 0; q < 4; ++q) {
            union { unsigned u; float f; } lo, hi;
            lo.u = dw[q] << 16;
            hi.u = dw[q] & 0xffff0000u;
            a[2 * q]     += lo.f;
            a[2 * q + 1] += hi.f;
        }
    }
    float4 o0 = {a[0], a[1], a[2], a[3]};
    float4 o1 = {a[4], a[5], a[6], a[7]};
    *(float4*)(out + (size_t)row * D + c)     = o0;
    *(float4*)(out + (size_t)row * D + c + 4) = o1;
}

__global__ __launch_bounds__(256) void segsum_bf16_dual(
    const unsigned short* __restrict__ Hf, const int* __restrict__ rpf,
    const int* __restrict__ esf, float* __restrict__ ou,
    const unsigned short* __restrict__ Hr, const int* __restrict__ rpr,
    const int* __restrict__ esr, float* __restrict__ oi,
    int nrows, int seg_grid)
{
    int bid = blockIdx.x;
    const unsigned short* H; const int* rp; const int* es; float* out;
    if (bid < seg_grid) { H = Hf; rp = rpf; es = esf; out = ou; }
    else { bid -= seg_grid; H = Hr; rp = rpr; es = esr; out = oi; }
    const int t = bid * 256 + threadIdx.x;
    const int row = t >> 4;
    if (row >= nrows) return;
    segsum_row(H, rp, es, out, row, t & 15);
}

// ---------------- host orchestration ----------------
static inline size_t align16(size_t x) { return (x + 15) & ~(size_t)15; }

extern "C" void kernel_launch(void* const* d_in, const int* in_sizes, int n_in,
                              void* d_out, int out_size, void* d_ws, size_t ws_size,
                              hipStream_t stream)
{
    const float* x_user = (const float*)d_in[0];
    // d_in[1] = x_item: unused (both relations source from users)
    const int*   ei_fol = (const int*)d_in[2];
    const int*   ei_rat = (const int*)d_in[3];
    const float* W0f = (const float*)d_in[4];
    const float* b0f = (const float*)d_in[5];
    // d_in[6..7]: W0_rates/b0_rates dead (layer-0 item output never consumed)
    const float* W1f = (const float*)d_in[8];
    const float* b1f = (const float*)d_in[9];
    const float* W1r = (const float*)d_in[10];
    const float* b1r = (const float*)d_in[11];

    const int n  = in_sizes[0] / D;   // 100000 (n < 2^18, <=131072 assumed)
    const int Ef = in_sizes[2] / 2;   // 600000
    const int Er = in_sizes[3] / 2;

    float* out_u = (float*)d_out;
    float* out_i = out_u + (size_t)n * D;

    // workspace layout; HC (3rd H buffer) only if scratch allows (~88 MB total)
    char* ws = (char*)d_ws;
    size_t off = 0;
    unsigned short* HA = (unsigned short*)(ws + off); off = align16(off + (size_t)n * D * 2);
    unsigned short* HB = (unsigned short*)(ws + off); off = align16(off + (size_t)n * D * 2);
    int* rpf   = (int*)(ws + off); off = align16(off + (size_t)(n + 1) * 4);
    int* rpr   = (int*)(ws + off); off = align16(off + (size_t)(n + 1) * 4);
    int* esf   = (int*)(ws + off); off = align16(off + (size_t)Ef * 4);
    int* esr   = (int*)(ws + off); off = align16(off + (size_t)Er * 4);
    unsigned* pkf = (unsigned*)(ws + off); off = align16(off + (size_t)Ef * 4);
    unsigned* pkr = (unsigned*)(ws + off); off = align16(off + (size_t)Er * 4);
    unsigned short* Wt0 = (unsigned short*)(ws + off); off = align16(off + (size_t)D * D * 2);
    unsigned short* Wt1 = (unsigned short*)(ws + off); off = align16(off + (size_t)D * D * 2);
    unsigned short* Wt2 = (unsigned short*)(ws + off); off = align16(off + (size_t)D * D * 2);
    int* gbc   = (int*)(ws + off); off = align16(off + 512 * 4);
    int* gbase = (int*)(ws + off); off = align16(off + 512 * 4);
    int* gcur  = (int*)(ws + off); off = align16(off + 512 * 4);
    unsigned short* HC = (unsigned short*)(ws + off);
    const bool big = (off + (size_t)n * D * 2) <= ws_size;

    const dim3 blk(256);
    const int gemm_grid = (n + 31) / 32;                           // 3125
    const int PB = 320;                                            // prehist blocks
    const int chunks_f = (Ef + CH - 1) / CH;
    const int chunks_r = (Er + CH - 1) / CH;
    const int seg_grid = (int)(((long long)n * 16 + 255) / 256);   // 6250

    hipMemsetAsync(gbc, 0, 512 * sizeof(int), stream);
    prep_w<<<24, blk, 0, stream>>>(W0f, W1f, W1r, Wt0, Wt1, Wt2);

    // K1: GEMM0 (H0 = relu(x_user@W0f+b0f)) fused with bucket prehist
    gemm0_prehist<<<gemm_grid + PB, blk, 0, stream>>>(
        x_user, Wt0, b0f, HA, n, gemm_grid, ei_fol + Ef, ei_rat + Er, Ef, Er, gbc);
    // CSR build for both relations
    scan_buckets<<<1, 256, 0, stream>>>(gbc, gbase, gcur, rpf + n, rpr + n, Ef, Er);
    bucket_scatter<<<chunks_f + chunks_r, blk, 0, stream>>>(
        ei_fol, ei_rat, Ef, Er, chunks_f, gcur, pkf, pkr);
    csr_finalize<<<512, blk, 0, stream>>>(pkf, pkr, gbase, Ef, Er, rpf, rpr, esf, esr, n);

    if (big) {
        // fused: U1 = segsum_f(H0) in-reg; H1f -> HB, H1r -> HC
        seg_dualgemm<<<gemm_grid, blk, 0, stream>>>(
            HA, rpf, esf, Wt1, b1f, HB, Wt2, b1r, HC, nullptr, n);
        segsum_bf16_dual<<<2 * seg_grid, blk, 0, stream>>>(
            HB, rpf, esf, out_u, HC, rpr, esr, out_i, n, seg_grid);
    } else {
        // tight scratch: fused writes U1 (staged in out_i) + H1f; second GEMM
        // reuses gemm0_prehist (grid==gemm_grid -> prehist branch never runs)
        seg_dualgemm<<<gemm_grid, blk, 0, stream>>>(
            HA, rpf, esf, Wt1, b1f, HB, nullptr, nullptr, nullptr, out_i, n);
        gemm0_prehist<<<gemm_grid, blk, 0, stream>>>(
            out_i, Wt2, b1r, HA, n, gemm_grid, ei_fol + Ef, ei_rat + Er, Ef, Er, gbc);
        segsum_bf16_dual<<<2 * seg_grid, blk, 0, stream>>>(
            HB, rpf, esf, out_u, HA, rpr, esr, out_i, n, seg_grid);
    }
}

// Round 6
// 396.271 us; speedup vs baseline: 1.0813x; 1.0813x over previous
//
#include <hip/hip_runtime.h>

#define D 128
#define RPB_BITS 9          // 512 rows per bucket; n<=131072 -> <=256 buckets
#define CH 8192             // edges per bucket_scatter block

typedef __attribute__((ext_vector_type(8))) short bf16x8;
typedef __attribute__((ext_vector_type(4))) float f32x4;

static __device__ __forceinline__ unsigned short f2bf(float f) {
    union { float f; unsigned u; } v; v.f = f;
    unsigned r = (v.u + 0x7fffu + ((v.u >> 16) & 1u)) >> 16;   // RNE
    return (unsigned short)r;
}
static __device__ __forceinline__ float bf2f(unsigned short s) {
    union { unsigned u; float f; } v; v.u = ((unsigned)s) << 16;
    return v.f;
}

// ---------------- W pre-conversion: fp32 [k][n] -> bf16 LDS image ----------------
__global__ __launch_bounds__(256) void prep_w(
    const float* __restrict__ Wa, const float* __restrict__ Wb, const float* __restrict__ Wc,
    unsigned short* __restrict__ Ta, unsigned short* __restrict__ Tb, unsigned short* __restrict__ Tc)
{
    const int m = blockIdx.x >> 3;
    const float* W = (m == 0) ? Wa : ((m == 1) ? Wb : Wc);
    unsigned short* T = (m == 0) ? Ta : ((m == 1) ? Tb : Tc);
    const int t = ((blockIdx.x & 7) << 8) + threadIdx.x;   // 0..2047
    const int n = t >> 4;
    const int k0 = (t & 15) << 3;
    bf16x8 hv;
    #pragma unroll
    for (int j = 0; j < 8; ++j)
        hv[j] = (short)f2bf(W[(size_t)(k0 + j) * D + n]);
    *(bf16x8*)&T[n * D + (k0 ^ ((n & 7) << 3))] = hv;
}

// ---------------- GEMM building blocks (BM=32, BN=128, K=128) ----------------
static __device__ __forceinline__ void stage_Wimg(
    const unsigned short* __restrict__ Wt, unsigned short* Wh, int tid)
{
    #pragma unroll
    for (int i = 0; i < 8; ++i) {
        const int e = (tid << 3) + (i << 11);
        *(uint4*)&Wh[e] = *(const uint4*)&Wt[e];
    }
}

static __device__ __forceinline__ void stage_X(
    const float* __restrict__ X, unsigned short* Xh, unsigned short* Xl,
    int row0, int nrows, int w, int l)
{
    const int k0 = (l & 15) << 3;
    #pragma unroll
    for (int i = 0; i < 2; ++i) {
        const int r = ((w + (i << 2)) << 2) + (l >> 4);   // 0..31
        bf16x8 hv, lv;
        if (row0 + r < nrows) {
            const float* xp = X + (size_t)(row0 + r) * D + k0;
            #pragma unroll
            for (int j = 0; j < 8; ++j) {
                float x = xp[j];
                unsigned short h = f2bf(x);
                hv[j] = (short)h;
                lv[j] = (short)f2bf(x - bf2f(h));   // split-bf16 residual
            }
        } else {
            #pragma unroll
            for (int j = 0; j < 8; ++j) { hv[j] = 0; lv[j] = 0; }
        }
        const int sw = k0 ^ ((r & 7) << 3);
        *(bf16x8*)&Xh[r * D + sw] = hv;
        *(bf16x8*)&Xl[r * D + sw] = lv;
    }
}

static __device__ __forceinline__ void mfma_compute(
    const unsigned short* Xh, const unsigned short* Xl, const unsigned short* Wh,
    f32x4 acc[4], int w, int l)
{
    const int rtile = (w >> 1) << 4;
    const int c0 = (w & 1) << 6;
    const int ra = rtile + (l & 15);
    #pragma unroll
    for (int kb = 0; kb < 4; ++kb) {
        const int kk0 = (kb << 5) + ((l >> 4) << 3);
        const int swa = kk0 ^ ((ra & 7) << 3);
        const bf16x8 ah = *(const bf16x8*)&Xh[ra * D + swa];
        const bf16x8 al = *(const bf16x8*)&Xl[ra * D + swa];
        #pragma unroll
        for (int ct = 0; ct < 4; ++ct) {
            const int n = c0 + (ct << 4) + (l & 15);
            const bf16x8 bh = *(const bf16x8*)&Wh[n * D + (kk0 ^ ((n & 7) << 3))];
            acc[ct] = __builtin_amdgcn_mfma_f32_16x16x32_bf16(ah, bh, acc[ct], 0, 0, 0);
            acc[ct] = __builtin_amdgcn_mfma_f32_16x16x32_bf16(al, bh, acc[ct], 0, 0, 0);
        }
    }
}

static __device__ __forceinline__ void epilogue_store(
    const f32x4 acc[4], const float* __restrict__ bias,
    unsigned short* __restrict__ H, int row0, int nrows, int w, int l)
{
    const int rtile = (w >> 1) << 4;
    const int c0 = (w & 1) << 6;
    #pragma unroll
    for (int ct = 0; ct < 4; ++ct) {
        const int col = c0 + (ct << 4) + (l & 15);
        const float bv = bias[col];
        #pragma unroll
        for (int j = 0; j < 4; ++j) {
            const int r = row0 + rtile + ((l >> 4) << 2) + j;
            if (r < nrows)
                H[(size_t)r * D + col] = f2bf(fmaxf(acc[ct][j] + bv, 0.f));
        }
    }
}

// ---------------- K1: GEMM0 blocks + bucket-prehist blocks fused ----------------
__global__ __launch_bounds__(256) void gemm0_prehist(
    const float* __restrict__ X, const unsigned short* __restrict__ Wt,
    const float* __restrict__ bias, unsigned short* __restrict__ H, int nrows,
    int gemm_grid,
    const int* __restrict__ dstf, const int* __restrict__ dstr,
    int Ef, int Er, int* __restrict__ gbc)
{
    __shared__ unsigned short Xh[32 * D];
    __shared__ unsigned short Xl[32 * D];
    __shared__ unsigned short Wh[128 * D];
    __shared__ int lcnt[512];
    const int tid = threadIdx.x;
    if ((int)blockIdx.x < gemm_grid) {
        const int w = tid >> 6, l = tid & 63;
        const int row0 = blockIdx.x * 32;
        stage_Wimg(Wt, Wh, tid);
        stage_X(X, Xh, Xl, row0, nrows, w, l);
        __syncthreads();
        f32x4 acc[4] = {};
        mfma_compute(Xh, Xl, Wh, acc, w, l);
        epilogue_store(acc, bias, H, row0, nrows, w, l);
    } else {
        lcnt[tid] = 0; lcnt[tid + 256] = 0;
        __syncthreads();
        const int nb = gridDim.x - gemm_grid;
        const int bid = blockIdx.x - gemm_grid;
        const int tot = Ef + Er;
        for (int i = bid * 256 + tid; i < tot; i += nb * 256) {
            int idx = (i < Ef) ? (dstf[i] >> RPB_BITS)
                               : (256 + (dstr[i - Ef] >> RPB_BITS));
            atomicAdd(&lcnt[idx], 1);
        }
        __syncthreads();
        if (lcnt[tid])       atomicAdd(&gbc[tid],       lcnt[tid]);
        if (lcnt[tid + 256]) atomicAdd(&gbc[tid + 256], lcnt[tid + 256]);
    }
}

// ---------------- K2: per-rel exclusive scan of 256 bucket counts ----------------
__global__ void scan_buckets(const int* __restrict__ gbc, int* __restrict__ gbase,
                             int* __restrict__ gcur, int* rpf_n, int* rpr_n,
                             int Ef, int Er)
{
    __shared__ int ts[256];
    const int t = threadIdx.x;
    for (int r = 0; r < 2; ++r) {
        int v = gbc[r * 256 + t];
        ts[t] = v; __syncthreads();
        int incl = v;
        for (int o = 1; o < 256; o <<= 1) {
            int y = (t >= o) ? ts[t - o] : 0;
            __syncthreads();
            incl += y; ts[t] = incl;
            __syncthreads();
        }
        gbase[r * 256 + t] = incl - v;
        gcur[r * 256 + t]  = incl - v;
        __syncthreads();
    }
    if (t == 0) { *rpf_n = Ef; *rpr_n = Er; }
}

// ---------------- K3: scatter edges into bucket-major packed form ----------------
__global__ __launch_bounds__(256) void bucket_scatter(
    const int* __restrict__ eif, const int* __restrict__ eir,
    int Ef, int Er, int chunks_f,
    int* __restrict__ gcur,
    unsigned* __restrict__ pk_f, unsigned* __restrict__ pk_r)
{
    __shared__ int cnt[256], off[256];
    const int t = threadIdx.x;
    const int cid = blockIdx.x;
    const int *src, *dst; unsigned* pk; int* cur; int base, E;
    if (cid < chunks_f) { base = cid * CH;              E = Ef; src = eif; dst = eif + Ef; pk = pk_f; cur = gcur; }
    else                { base = (cid - chunks_f) * CH; E = Er; src = eir; dst = eir + Er; pk = pk_r; cur = gcur + 256; }
    cnt[t] = 0;
    __syncthreads();
    for (int k = 0; k < CH / 256; ++k) {
        int e = base + t + k * 256;
        if (e < E) atomicAdd(&cnt[dst[e] >> RPB_BITS], 1);
    }
    __syncthreads();
    { int c = cnt[t]; if (c) off[t] = atomicAdd(&cur[t], c); }
    __syncthreads();
    for (int k = 0; k < CH / 256; ++k) {
        int e = base + t + k * 256;
        if (e < E) {
            int d = dst[e];
            int p = atomicAdd(&off[d >> RPB_BITS], 1);
            pk[p] = (unsigned)src[e] | ((unsigned)(d & 511) << 18);
        }
    }
}

// ---------------- K4: per-bucket CSR finalize (rowptr + esrc) ----------------
__global__ __launch_bounds__(256) void csr_finalize(
    const unsigned* __restrict__ pk_f, const unsigned* __restrict__ pk_r,
    const int* __restrict__ gbase, int Ef, int Er,
    int* __restrict__ rpf, int* __restrict__ rpr,
    int* __restrict__ esf, int* __restrict__ esr, int n)
{
    __shared__ int deg[512], cur[512], ts[256];
    const int t = threadIdx.x;
    const int rel = (int)blockIdx.x >> 8;
    const int b = (int)blockIdx.x & 255;
    const unsigned* pk = rel ? pk_r : pk_f;
    int* rp = rel ? rpr : rpf;
    int* es = rel ? esr : esf;
    const int E = rel ? Er : Ef;
    const int* gb = gbase + rel * 256;
    const int beg = gb[b];
    const int end = (b == 255) ? E : gb[b + 1];
    deg[t] = 0; deg[t + 256] = 0;
    __syncthreads();
    for (int j = beg + t; j < end; j += 256)
        atomicAdd(&deg[pk[j] >> 18], 1);
    __syncthreads();
    const int a0 = deg[2 * t], a1 = deg[2 * t + 1];
    const int s = a0 + a1;
    ts[t] = s; __syncthreads();
    int incl = s;
    for (int o = 1; o < 256; o <<= 1) {
        int y = (t >= o) ? ts[t - o] : 0;
        __syncthreads();
        incl += y; ts[t] = incl;
        __syncthreads();
    }
    const int ex = incl - s;
    const int row0 = b << RPB_BITS;
    if (row0 + 2 * t < n)     rp[row0 + 2 * t]     = beg + ex;
    if (row0 + 2 * t + 1 < n) rp[row0 + 2 * t + 1] = beg + ex + a0;
    cur[2 * t] = ex; cur[2 * t + 1] = ex + a0;
    __syncthreads();
    for (int j = beg + t; j < end; j += 256) {
        unsigned v = pk[j];
        int p = atomicAdd(&cur[v >> 18], 1);
        es[beg + p] = (int)(v & 0x3ffffu);
    }
}

// ---------------- fused: U1-tile segsum (regs) -> split-bf16 LDS -> dual GEMM ----
// Single Wh buffer (48 KB LDS -> 3 blocks/CU); W restaged between passes.
__global__ __launch_bounds__(256) void seg_dualgemm(
    const unsigned short* __restrict__ H0,
    const int* __restrict__ rp, const int* __restrict__ es,
    const unsigned short* __restrict__ Wt1, const float* __restrict__ b1,
    unsigned short* __restrict__ H1,
    const unsigned short* __restrict__ Wt2, const float* __restrict__ b2,
    unsigned short* __restrict__ H2,
    float* __restrict__ U1out, int nrows)
{
    __shared__ unsigned short Xh[32 * D];
    __shared__ unsigned short Xl[32 * D];
    __shared__ unsigned short Wh[128 * D];   // single buffer: 48 KB total
    const int tid = threadIdx.x;
    const int row0 = blockIdx.x * 32;

    stage_Wimg(Wt1, Wh, tid);

    // segsum into registers: 8 lanes/row, 16 cols/lane, 2-edge unroll (ILP=4 loads)
    const int rl = tid >> 3;              // local row 0..31
    const int r = row0 + rl;
    const int c0 = (tid & 7) << 4;        // col base
    float a[16];
    #pragma unroll
    for (int q = 0; q < 16; ++q) a[q] = 0.f;
    if (r < nrows) {
        const int beg = rp[r], end = rp[r + 1];
        int j = beg;
        for (; j + 2 <= end; j += 2) {
            const unsigned short* hp0 = H0 + (size_t)es[j]     * D + c0;
            const unsigned short* hp1 = H0 + (size_t)es[j + 1] * D + c0;
            const uint4 u0 = *(const uint4*)hp0;
            const uint4 u1 = *(const uint4*)(hp0 + 8);
            const uint4 u2 = *(const uint4*)hp1;
            const uint4 u3 = *(const uint4*)(hp1 + 8);
            const unsigned dwA[8] = {u0.x, u0.y, u0.z, u0.w, u1.x, u1.y, u1.z, u1.w};
            const unsigned dwB[8] = {u2.x, u2.y, u2.z, u2.w, u3.x, u3.y, u3.z, u3.w};
            #pragma unroll
            for (int q = 0; q < 8; ++q) {
                union { unsigned u; float f; } lo, hi;
                lo.u = dwA[q] << 16; hi.u = dwA[q] & 0xffff0000u;
                a[2 * q] += lo.f; a[2 * q + 1] += hi.f;
                lo.u = dwB[q] << 16; hi.u = dwB[q] & 0xffff0000u;
                a[2 * q] += lo.f; a[2 * q + 1] += hi.f;
            }
        }
        if (j < end) {
            const unsigned short* hp = H0 + (size_t)es[j] * D + c0;
            const uint4 u0 = *(const uint4*)hp;
            const uint4 u1 = *(const uint4*)(hp + 8);
            const unsigned dw[8] = {u0.x, u0.y, u0.z, u0.w, u1.x, u1.y, u1.z, u1.w};
            #pragma unroll
            for (int q = 0; q < 8; ++q) {
                union { unsigned u; float f; } lo, hi;
                lo.u = dw[q] << 16; hi.u = dw[q] & 0xffff0000u;
                a[2 * q] += lo.f; a[2 * q + 1] += hi.f;
            }
        }
        if (U1out) {
            float4* up = (float4*)(U1out + (size_t)r * D + c0);
            up[0] = make_float4(a[0], a[1], a[2], a[3]);
            up[1] = make_float4(a[4], a[5], a[6], a[7]);
            up[2] = make_float4(a[8], a[9], a[10], a[11]);
            up[3] = make_float4(a[12], a[13], a[14], a[15]);
        }
    }

    // split-bf16 into LDS (two octets: c0, c0+8)
    bf16x8 hv0, lv0, hv1, lv1;
    #pragma unroll
    for (int q = 0; q < 8; ++q) {
        unsigned short h0 = f2bf(a[q]);
        hv0[q] = (short)h0; lv0[q] = (short)f2bf(a[q] - bf2f(h0));
        unsigned short h1 = f2bf(a[q + 8]);
        hv1[q] = (short)h1; lv1[q] = (short)f2bf(a[q + 8] - bf2f(h1));
    }
    const int sw0 = c0 ^ ((rl & 7) << 3);
    const int sw1 = (c0 + 8) ^ ((rl & 7) << 3);
    *(bf16x8*)&Xh[rl * D + sw0] = hv0;
    *(bf16x8*)&Xl[rl * D + sw0] = lv0;
    *(bf16x8*)&Xh[rl * D + sw1] = hv1;
    *(bf16x8*)&Xl[rl * D + sw1] = lv1;
    __syncthreads();

    const int w = tid >> 6, l = tid & 63;
    {
        f32x4 acc[4] = {};
        mfma_compute(Xh, Xl, Wh, acc, w, l);
        epilogue_store(acc, b1, H1, row0, nrows, w, l);
    }
    if (Wt2) {
        __syncthreads();               // pass-1 Wh reads done
        stage_Wimg(Wt2, Wh, tid);
        __syncthreads();               // Wh refilled
        f32x4 acc[4] = {};
        mfma_compute(Xh, Xl, Wh, acc, w, l);
        epilogue_store(acc, b2, H2, row0, nrows, w, l);
    }
}

// ---------------- segmented sum over bf16 H -> fp32 out (final, both rels) ------
static __device__ __forceinline__ void segsum_row(
    const unsigned short* __restrict__ H, const int* __restrict__ rp,
    const int* __restrict__ es, float* __restrict__ out, int row, int lane16)
{
    const int c = lane16 << 3;
    float a[8] = {0.f,0.f,0.f,0.f,0.f,0.f,0.f,0.f};
    const int beg = rp[row], end = rp[row + 1];
    int j = beg;
    for (; j + 2 <= end; j += 2) {        // 2-edge unroll: 2 loads in flight
        const uint4 v0 = *(const uint4*)(H + (size_t)es[j]     * D + c);
        const uint4 v1 = *(const uint4*)(H + (size_t)es[j + 1] * D + c);
        const unsigned dwA[4] = {v0.x, v0.y, v0.z, v0.w};
        const unsigned dwB[4] = {v1.x, v1.y, v1.z, v1.w};
        #pragma unroll
        for (int q = 0; q < 4; ++q) {
            union { unsigned u; float f; } lo, hi;
            lo.u = dwA[q] << 16; hi.u = dwA[q] & 0xffff0000u;
            a[2 * q] += lo.f; a[2 * q + 1] += hi.f;
            lo.u = dwB[q] << 16; hi.u = dwB[q] & 0xffff0000u;
            a[2 * q] += lo.f; a[2 * q + 1] += hi.f;
        }
    }
    if (j < end) {
        const uint4 v = *(const uint4*)(H + (size_t)es[j] * D + c);
        const unsigned dw[4] = {v.x, v.y, v.z, v.w};
        #pragma unroll
        for (int q = 0; q < 4; ++q) {
            union { unsigned u; float f; } lo, hi;
            lo.u = dw[q] << 16;
            hi.u = dw[q] & 0xffff0000u;
            a[2 * q]     += lo.f;
            a[2 * q + 1] += hi.f;
        }
    }
    float4 o0 = {a[0], a[1], a[2], a[3]};
    float4 o1 = {a[4], a[5], a[6], a[7]};
    *(float4*)(out + (size_t)row * D + c)     = o0;
    *(float4*)(out + (size_t)row * D + c + 4) = o1;
}

__global__ __launch_bounds__(256) void segsum_bf16_dual(
    const unsigned short* __restrict__ Hf, const int* __restrict__ rpf,
    const int* __restrict__ esf, float* __restrict__ ou,
    const unsigned short* __restrict__ Hr, const int* __restrict__ rpr,
    const int* __restrict__ esr, float* __restrict__ oi,
    int nrows, int seg_grid)
{
    int bid = blockIdx.x;
    const unsigned short* H; const int* rp; const int* es; float* out;
    if (bid < seg_grid) { H = Hf; rp = rpf; es = esf; out = ou; }
    else { bid -= seg_grid; H = Hr; rp = rpr; es = esr; out = oi; }
    const int t = bid * 256 + threadIdx.x;
    const int row = t >> 4;
    if (row >= nrows) return;
    segsum_row(H, rp, es, out, row, t & 15);
}

// ---------------- host orchestration ----------------
static inline size_t align16(size_t x) { return (x + 15) & ~(size_t)15; }

extern "C" void kernel_launch(void* const* d_in, const int* in_sizes, int n_in,
                              void* d_out, int out_size, void* d_ws, size_t ws_size,
                              hipStream_t stream)
{
    const float* x_user = (const float*)d_in[0];
    // d_in[1] = x_item: unused (both relations source from users)
    const int*   ei_fol = (const int*)d_in[2];
    const int*   ei_rat = (const int*)d_in[3];
    const float* W0f = (const float*)d_in[4];
    const float* b0f = (const float*)d_in[5];
    // d_in[6..7]: W0_rates/b0_rates dead (layer-0 item output never consumed)
    const float* W1f = (const float*)d_in[8];
    const float* b1f = (const float*)d_in[9];
    const float* W1r = (const float*)d_in[10];
    const float* b1r = (const float*)d_in[11];

    const int n  = in_sizes[0] / D;   // 100000 (n < 2^18, <=131072 assumed)
    const int Ef = in_sizes[2] / 2;   // 600000
    const int Er = in_sizes[3] / 2;

    float* out_u = (float*)d_out;
    float* out_i = out_u + (size_t)n * D;

    // workspace layout; HC (3rd H buffer) only if scratch allows (~88 MB total)
    char* ws = (char*)d_ws;
    size_t off = 0;
    unsigned short* HA = (unsigned short*)(ws + off); off = align16(off + (size_t)n * D * 2);
    unsigned short* HB = (unsigned short*)(ws + off); off = align16(off + (size_t)n * D * 2);
    int* rpf   = (int*)(ws + off); off = align16(off + (size_t)(n + 1) * 4);
    int* rpr   = (int*)(ws + off); off = align16(off + (size_t)(n + 1) * 4);
    int* esf   = (int*)(ws + off); off = align16(off + (size_t)Ef * 4);
    int* esr   = (int*)(ws + off); off = align16(off + (size_t)Er * 4);
    unsigned* pkf = (unsigned*)(ws + off); off = align16(off + (size_t)Ef * 4);
    unsigned* pkr = (unsigned*)(ws + off); off = align16(off + (size_t)Er * 4);
    unsigned short* Wt0 = (unsigned short*)(ws + off); off = align16(off + (size_t)D * D * 2);
    unsigned short* Wt1 = (unsigned short*)(ws + off); off = align16(off + (size_t)D * D * 2);
    unsigned short* Wt2 = (unsigned short*)(ws + off); off = align16(off + (size_t)D * D * 2);
    int* gbc   = (int*)(ws + off); off = align16(off + 512 * 4);
    int* gbase = (int*)(ws + off); off = align16(off + 512 * 4);
    int* gcur  = (int*)(ws + off); off = align16(off + 512 * 4);
    unsigned short* HC = (unsigned short*)(ws + off);
    const bool big = (off + (size_t)n * D * 2) <= ws_size;

    const dim3 blk(256);
    const int gemm_grid = (n + 31) / 32;                           // 3125
    const int PB = 320;                                            // prehist blocks
    const int chunks_f = (Ef + CH - 1) / CH;
    const int chunks_r = (Er + CH - 1) / CH;
    const int seg_grid = (int)(((long long)n * 16 + 255) / 256);   // 6250

    hipMemsetAsync(gbc, 0, 512 * sizeof(int), stream);
    prep_w<<<24, blk, 0, stream>>>(W0f, W1f, W1r, Wt0, Wt1, Wt2);

    // K1: GEMM0 (H0 = relu(x_user@W0f+b0f)) fused with bucket prehist
    gemm0_prehist<<<gemm_grid + PB, blk, 0, stream>>>(
        x_user, Wt0, b0f, HA, n, gemm_grid, ei_fol + Ef, ei_rat + Er, Ef, Er, gbc);
    // CSR build for both relations
    scan_buckets<<<1, 256, 0, stream>>>(gbc, gbase, gcur, rpf + n, rpr + n, Ef, Er);
    bucket_scatter<<<chunks_f + chunks_r, blk, 0, stream>>>(
        ei_fol, ei_rat, Ef, Er, chunks_f, gcur, pkf, pkr);
    csr_finalize<<<512, blk, 0, stream>>>(pkf, pkr, gbase, Ef, Er, rpf, rpr, esf, esr, n);

    if (big) {
        // fused: U1 = segsum_f(H0) in-reg; H1f -> HB, H1r -> HC
        seg_dualgemm<<<gemm_grid, blk, 0, stream>>>(
            HA, rpf, esf, Wt1, b1f, HB, Wt2, b1r, HC, nullptr, n);
        segsum_bf16_dual<<<2 * seg_grid, blk, 0, stream>>>(
            HB, rpf, esf, out_u, HC, rpr, esr, out_i, n, seg_grid);
    } else {
        // tight scratch: fused writes U1 (staged in out_i) + H1f; second GEMM
        // reuses gemm0_prehist (grid==gemm_grid -> prehist branch never runs)
        seg_dualgemm<<<gemm_grid, blk, 0, stream>>>(
            HA, rpf, esf, Wt1, b1f, HB, nullptr, nullptr, nullptr, out_i, n);
        gemm0_prehist<<<gemm_grid, blk, 0, stream>>>(
            out_i, Wt2, b1r, HA, n, gemm_grid, ei_fol + Ef, ei_rat + Er, Ef, Er, gbc);
        segsum_bf16_dual<<<2 * seg_grid, blk, 0, stream>>>(
            HB, rpf, esf, out_u, HA, rpr, esr, out_i, n, seg_grid);
    }
}